// Round 2
// baseline (70.850 us; speedup 1.0000x reference)
//
#include <hip/hip_runtime.h>
#include <stdint.h>
#include <stddef.h>

#define NB 8
#define SS 512
#define HID 1024
#define NHEADS 12
#define HSZ 64
#define NPROJ 1536
#define MROWS 4096
#define NEG_INF 1000000000000.0f

typedef __attribute__((ext_vector_type(4))) float f32x4;
typedef __attribute__((ext_vector_type(8))) __bf16 bf16x8;
typedef __attribute__((ext_vector_type(4))) unsigned short us4;

typedef __attribute__((address_space(1))) unsigned char gu8;
typedef __attribute__((address_space(3))) unsigned char lu8;

static __device__ __forceinline__ void gld16(const void* g, void* l) {
  __builtin_amdgcn_global_load_lds((gu8*)(g), (lu8*)(l), 16, 0, 0);
}

static __device__ __forceinline__ unsigned short f2bf(float f) {
  union { float f; unsigned u; } x; x.f = f;
  unsigned r = x.u + 0x7fffu + ((x.u >> 16) & 1u);
  return (unsigned short)(r >> 16);
}

// ---- merged prep: [0,64) table | [64, 64+4096) cvtx | [4160, 4160+1536) wt
__global__ __launch_bounds__(256) void k_prep(
    const float4* __restrict__ x, const float* __restrict__ W,
    float2* __restrict__ tab, us4* __restrict__ xb, unsigned short* __restrict__ wbt) {
  __shared__ float t[32][33];
  const int bid = blockIdx.x;
  const int tid = threadIdx.x;
  if (bid < 64) {
    // sincos table: tab[s*32+i] = (sin(s*rate_i), cos(s*rate_i))
    int tt = bid * 256 + tid;
    int s = tt >> 5, i = tt & 31;
    float rate = powf(10000.0f, -(float)i / 32.0f);
    float sv, cv;
    sincosf((float)s * rate, &sv, &cv);
    tab[tt] = make_float2(sv, cv);
  } else if (bid < 64 + 4096) {
    // x f32 -> bf16, 4/thread
    int i = (bid - 64) * 256 + tid;
    float4 v = x[i];
    us4 o;
    o[0] = f2bf(v.x); o[1] = f2bf(v.y); o[2] = f2bf(v.z); o[3] = f2bf(v.w);
    xb[i] = o;
  } else {
    // W (1024 x 1536 f32) -> WbT (1536 x 1024 bf16)
    int flat = bid - (64 + 4096);
    int n0 = (flat % 48) * 32, k0 = (flat / 48) * 32;
    int tx = tid & 31, ty = tid >> 5;  // 32x8
#pragma unroll
    for (int i = 0; i < 4; ++i)
      t[ty + i * 8][tx] = W[(k0 + ty + i * 8) * NPROJ + n0 + tx];
    __syncthreads();
#pragma unroll
    for (int i = 0; i < 4; ++i)
      wbt[(n0 + ty + i * 8) * HID + (k0 + tx)] = f2bf(t[tx][ty + i * 8]);
  }
}

// ---- GEMM1: proj = xb(4096x1024) * WbT(1536x1024)^T, fused bias + RoPE -> q,k bf16
// LDS tiles [128 rows][64 k] bf16, XOR-swizzled: byte (row,cb) holds data (row, cb^((row&7)<<4))
__global__ __launch_bounds__(256) void k_proj(
    const unsigned short* __restrict__ xb, const unsigned short* __restrict__ wbt,
    const float* __restrict__ bias, const float2* __restrict__ tab,
    unsigned short* __restrict__ qo, unsigned short* __restrict__ ko) {
  __shared__ __align__(16) unsigned short lA[128 * 64];
  __shared__ __align__(16) unsigned short lB[128 * 64];
  const int tid = threadIdx.x;
  const int lane = tid & 63, w = tid >> 6;
  const int wm = w >> 1, wn = w & 1;
  const int m0 = blockIdx.x * 128, n0 = blockIdx.y * 128;

  f32x4 acc[4][4];
#pragma unroll
  for (int a = 0; a < 4; ++a)
#pragma unroll
    for (int bb = 0; bb < 4; ++bb)
      acc[a][bb] = (f32x4)(0.0f);

  int srow[4], soff[4];
#pragma unroll
  for (int c = 0; c < 4; ++c) {
    int lin = (w * 4 + c) * 1024 + lane * 16;
    int row = lin >> 7;
    int cb = lin & 127;
    srow[c] = row;
    soff[c] = cb ^ ((row & 7) << 4);  // pre-swizzled source, linear LDS dest
  }

  for (int kt = 0; kt < HID / 64; ++kt) {
#pragma unroll
    for (int c = 0; c < 4; ++c) {
      int chunk = w * 4 + c;
      gld16((const char*)(xb + (m0 + srow[c]) * HID + kt * 64) + soff[c],
            (char*)lA + chunk * 1024);
      gld16((const char*)(wbt + (n0 + srow[c]) * HID + kt * 64) + soff[c],
            (char*)lB + chunk * 1024);
    }
    __syncthreads();
#pragma unroll
    for (int ks = 0; ks < 2; ++ks) {
      bf16x8 af[4], bfr[4];
      const int kb = ks * 64 + (lane >> 4) * 16;
#pragma unroll
      for (int mi = 0; mi < 4; ++mi) {
        int row = wm * 64 + mi * 16 + (lane & 15);
        af[mi] = *(const bf16x8*)((const char*)lA + row * 128 + (kb ^ ((row & 7) << 4)));
      }
#pragma unroll
      for (int ni = 0; ni < 4; ++ni) {
        int row = wn * 64 + ni * 16 + (lane & 15);
        bfr[ni] = *(const bf16x8*)((const char*)lB + row * 128 + (kb ^ ((row & 7) << 4)));
      }
#pragma unroll
      for (int mi = 0; mi < 4; ++mi)
#pragma unroll
        for (int ni = 0; ni < 4; ++ni)
          acc[mi][ni] = __builtin_amdgcn_mfma_f32_16x16x32_bf16(af[mi], bfr[ni], acc[mi][ni], 0, 0, 0);
    }
    __syncthreads();
  }

  // epilogue: + bias, RoPE (pair col^1 lives in lane^1), scatter bf16 to q/k [b][h][s][d]
#pragma unroll
  for (int mi = 0; mi < 4; ++mi) {
#pragma unroll
    for (int ni = 0; ni < 4; ++ni) {
      const int col = n0 + wn * 64 + ni * 16 + (lane & 15);
      const float bv = bias[col];
      const int d = col & 63;
      const int h = col >> 7;
      const int j = col & 127;  // j<64 -> q, else k (wave-uniform)
      unsigned short* dst = (j < HSZ) ? qo : ko;
      const float sgn = (d & 1) ? 1.0f : -1.0f;
#pragma unroll
      for (int r = 0; r < 4; ++r) {
        const int row = m0 + wm * 64 + mi * 16 + (lane >> 4) * 4 + r;
        const int s = row & (SS - 1);
        const int bidx = row >> 9;
        float v = acc[mi][ni][r] + bv;
        float p = __shfl_xor(v, 1, 64);
        float2 sc = tab[s * 32 + (d & 31)];
        float o = v * sc.y + sgn * p * sc.x;
        dst[((bidx * NHEADS + h) * SS + s) * HSZ + d] = f2bf(o);
      }
    }
  }
}

// ---- GEMM2: logits[b,h,m,n] = dot(q[bh][m], k[bh][n]) with mask/causal/scale
__global__ __launch_bounds__(256) void k_logits(
    const unsigned short* __restrict__ q, const unsigned short* __restrict__ kk,
    const float* __restrict__ mask, float* __restrict__ out) {
  __shared__ __align__(16) unsigned short lQ[128 * 64];
  __shared__ __align__(16) unsigned short lK[128 * 64];
  const int tid = threadIdx.x;
  const int lane = tid & 63, w = tid >> 6;
  const int wm = w >> 1, wn = w & 1;
  const int bh = blockIdx.y;
  const int b = bh / NHEADS;
  const int m0 = (blockIdx.x >> 2) * 128, n0 = (blockIdx.x & 3) * 128;
  const char* qbase = (const char*)(q + (size_t)bh * SS * HSZ) + m0 * 128;
  const char* kbase = (const char*)(kk + (size_t)bh * SS * HSZ) + n0 * 128;

#pragma unroll
  for (int c = 0; c < 4; ++c) {
    int chunk = w * 4 + c;
    int lin = chunk * 1024 + lane * 16;
    int row = lin >> 7, cb = lin & 127;
    int sw = cb ^ ((row & 7) << 4);
    gld16(qbase + row * 128 + sw, (char*)lQ + chunk * 1024);
    gld16(kbase + row * 128 + sw, (char*)lK + chunk * 1024);
  }
  __syncthreads();

  f32x4 acc[4][4];
#pragma unroll
  for (int a = 0; a < 4; ++a)
#pragma unroll
    for (int bb = 0; bb < 4; ++bb)
      acc[a][bb] = (f32x4)(0.0f);

#pragma unroll
  for (int ks = 0; ks < 2; ++ks) {
    bf16x8 af[4], bfr[4];
    const int kb = ks * 64 + (lane >> 4) * 16;
#pragma unroll
    for (int mi = 0; mi < 4; ++mi) {
      int row = wm * 64 + mi * 16 + (lane & 15);
      af[mi] = *(const bf16x8*)((const char*)lQ + row * 128 + (kb ^ ((row & 7) << 4)));
    }
#pragma unroll
    for (int ni = 0; ni < 4; ++ni) {
      int row = wn * 64 + ni * 16 + (lane & 15);
      bfr[ni] = *(const bf16x8*)((const char*)lK + row * 128 + (kb ^ ((row & 7) << 4)));
    }
#pragma unroll
    for (int mi = 0; mi < 4; ++mi)
#pragma unroll
      for (int ni = 0; ni < 4; ++ni)
        acc[mi][ni] = __builtin_amdgcn_mfma_f32_16x16x32_bf16(af[mi], bfr[ni], acc[mi][ni], 0, 0, 0);
  }

  float mc[4];
#pragma unroll
  for (int ni = 0; ni < 4; ++ni)
    mc[ni] = mask[b * SS + n0 + wn * 64 + ni * 16 + (lane & 15)];
#pragma unroll
  for (int mi = 0; mi < 4; ++mi) {
#pragma unroll
    for (int r = 0; r < 4; ++r) {
      const int m = m0 + wm * 64 + mi * 16 + (lane >> 4) * 4 + r;
      const float mr = mask[b * SS + m];
#pragma unroll
      for (int ni = 0; ni < 4; ++ni) {
        const int n = n0 + wn * 64 + ni * 16 + (lane & 15);
        float v = acc[mi][ni][r];
        v = v * mr - NEG_INF * (1.0f - mr);
        v = v * mc[ni] - NEG_INF * (1.0f - mc[ni]);
        if (m > n) v -= NEG_INF;
        v *= 0.125f;
        __builtin_nontemporal_store(v, &out[((size_t)bh * SS + m) * SS + n]);
      }
    }
  }
}

extern "C" void kernel_launch(void* const* d_in, const int* in_sizes, int n_in,
                              void* d_out, int out_size, void* d_ws, size_t ws_size,
                              hipStream_t stream) {
  const float* x = (const float*)d_in[0];
  const float* mask = (const float*)d_in[1];
  const float* W = (const float*)d_in[2];
  const float* bias = (const float*)d_in[3];
  float* out = (float*)d_out;

  char* ws = (char*)d_ws;
  float2* tab = (float2*)ws;                                   // 128 KB
  unsigned short* xb = (unsigned short*)(ws + 131072);         // 8 MB
  unsigned short* wbt = (unsigned short*)(ws + 131072 + 8388608);          // 3 MB
  unsigned short* qo = (unsigned short*)(ws + 131072 + 8388608 + 3145728); // 6.29 MB
  unsigned short* ko = (unsigned short*)(ws + 131072 + 8388608 + 3145728 + 6291456);

  k_prep<<<dim3(64 + 4096 + 1536), dim3(256), 0, stream>>>(
      (const float4*)x, W, tab, (us4*)xb, wbt);
  k_proj<<<dim3(32, 12), dim3(256), 0, stream>>>(xb, wbt, bias, tab, qo, ko);
  k_logits<<<dim3(16, 96), dim3(256), 0, stream>>>(qo, ko, mask, out);
}

// Round 3
// 66.046 us; speedup vs baseline: 1.0727x; 1.0727x over previous
//
#include <hip/hip_runtime.h>
#include <stdint.h>
#include <stddef.h>

#define SS 512
#define HID 1024
#define NHEADS 12
#define HSZ 64
#define NPROJ 1536
#define NEG_INF 1000000000000.0f

typedef __attribute__((ext_vector_type(4))) float f32x4;
typedef __attribute__((ext_vector_type(8))) __bf16 bf16x8;
typedef __attribute__((ext_vector_type(4))) unsigned short us4;

typedef __attribute__((address_space(1))) unsigned char gu8;
typedef __attribute__((address_space(3))) unsigned char lu8;

static __device__ __forceinline__ void gld16(const void* g, void* l) {
  __builtin_amdgcn_global_load_lds((gu8*)(g), (lu8*)(l), 16, 0, 0);
}

static __device__ __forceinline__ unsigned short f2bf(float f) {
  union { float f; unsigned u; } x; x.f = f;
  unsigned r = x.u + 0x7fffu + ((x.u >> 16) & 1u);
  return (unsigned short)(r >> 16);
}

// ---- merged prep: [0,64) sincos table | [64,4160) x->bf16 | [4160,5696) W^T->bf16
__global__ __launch_bounds__(256) void k_prep(
    const float4* __restrict__ x, const float* __restrict__ W,
    float2* __restrict__ tab, us4* __restrict__ xb, unsigned short* __restrict__ wbt) {
  __shared__ float t[32][33];
  const int bid = blockIdx.x;
  const int tid = threadIdx.x;
  if (bid < 64) {
    int tt = bid * 256 + tid;
    int s = tt >> 5, i = tt & 31;
    float rate = powf(10000.0f, -(float)i / 32.0f);
    float sv, cv;
    sincosf((float)s * rate, &sv, &cv);
    tab[tt] = make_float2(sv, cv);
  } else if (bid < 64 + 4096) {
    int i = (bid - 64) * 256 + tid;
    float4 v = x[i];
    us4 o;
    o[0] = f2bf(v.x); o[1] = f2bf(v.y); o[2] = f2bf(v.z); o[3] = f2bf(v.w);
    xb[i] = o;
  } else {
    int flat = bid - (64 + 4096);
    int n0 = (flat % 48) * 32, k0 = (flat / 48) * 32;
    int tx = tid & 31, ty = tid >> 5;
#pragma unroll
    for (int i = 0; i < 4; ++i)
      t[ty + i * 8][tx] = W[(k0 + ty + i * 8) * NPROJ + n0 + tx];
    __syncthreads();
#pragma unroll
    for (int i = 0; i < 4; ++i)
      wbt[(n0 + ty + i * 8) * HID + (k0 + tx)] = f2bf(t[tx][ty + i * 8]);
  }
}

// ---- GEMM1: proj^T tiles. A-operand = W rows (n), B-operand = x rows (m).
// Tile: M=128 x-rows, N=96 proj-cols, BK=64. grid (32,16) = 512 blocks = 2/CU.
// 2-phase double-buffered pipeline; XOR-swizzled LDS (linear dest + preswizzled src).
__global__ __launch_bounds__(256) void k_proj(
    const unsigned short* __restrict__ xb, const unsigned short* __restrict__ wbt,
    const float* __restrict__ bias, const float2* __restrict__ tab,
    unsigned short* __restrict__ qo, unsigned short* __restrict__ ko) {
  __shared__ __align__(16) unsigned short lA[2][128 * 64];  // x tile
  __shared__ __align__(16) unsigned short lB[2][96 * 64];   // W tile
  const int tid = threadIdx.x;
  const int lane = tid & 63, w = tid >> 6;
  const int wm = w >> 1, wn = w & 1;   // wm: m-half (64), wn: n-half (48)
  const int m0 = blockIdx.x * 128, n0 = blockIdx.y * 96;

  // staging: A = 16 KB = 16 wave-chunks (4/wave); B = 12 KB = 12 chunks (3/wave)
  const char* aptr[4]; const char* bptr[3];
  int adst[4], bdst[3];
#pragma unroll
  for (int c = 0; c < 4; ++c) {
    int lin = (w * 4 + c) * 1024 + lane * 16;
    int row = lin >> 7, cb = lin & 127;
    aptr[c] = (const char*)(xb + (size_t)(m0 + row) * HID) + (cb ^ ((row & 7) << 4));
    adst[c] = (w * 4 + c) * 1024;
  }
#pragma unroll
  for (int c = 0; c < 3; ++c) {
    int lin = (w * 3 + c) * 1024 + lane * 16;
    int row = lin >> 7, cb = lin & 127;
    bptr[c] = (const char*)(wbt + (size_t)(n0 + row) * HID) + (cb ^ ((row & 7) << 4));
    bdst[c] = (w * 3 + c) * 1024;
  }

  f32x4 acc[3][4];
#pragma unroll
  for (int a = 0; a < 3; ++a)
#pragma unroll
    for (int b = 0; b < 4; ++b)
      acc[a][b] = (f32x4)(0.0f);

#define STAGE(buf, kt)                                                      \
  do {                                                                      \
    _Pragma("unroll") for (int c = 0; c < 4; ++c)                           \
        gld16(aptr[c] + (kt) * 128, (char*)(&lA[(buf)][0]) + adst[c]);      \
    _Pragma("unroll") for (int c = 0; c < 3; ++c)                           \
        gld16(bptr[c] + (kt) * 128, (char*)(&lB[(buf)][0]) + bdst[c]);      \
  } while (0)

  STAGE(0, 0);
  asm volatile("s_waitcnt vmcnt(0)" ::: "memory");
  __builtin_amdgcn_s_barrier();

  for (int kt = 0; kt < 16; ++kt) {
    const int cur = kt & 1;
    if (kt < 15) STAGE(cur ^ 1, kt + 1);
#pragma unroll
    for (int ks = 0; ks < 2; ++ks) {
      bf16x8 af[3], bf[4];
      const int kb = ks * 64 + (lane >> 4) * 16;
#pragma unroll
      for (int a = 0; a < 3; ++a) {
        int row = wn * 48 + a * 16 + (lane & 15);
        af[a] = *(const bf16x8*)((const char*)(&lB[cur][0]) + row * 128 + (kb ^ ((row & 7) << 4)));
      }
#pragma unroll
      for (int b = 0; b < 4; ++b) {
        int row = wm * 64 + b * 16 + (lane & 15);
        bf[b] = *(const bf16x8*)((const char*)(&lA[cur][0]) + row * 128 + (kb ^ ((row & 7) << 4)));
      }
#pragma unroll
      for (int a = 0; a < 3; ++a)
#pragma unroll
        for (int b = 0; b < 4; ++b)
          acc[a][b] = __builtin_amdgcn_mfma_f32_16x16x32_bf16(af[a], bf[b], acc[a][b], 0, 0, 0);
    }
    asm volatile("s_waitcnt vmcnt(0)" ::: "memory");
    __builtin_amdgcn_s_barrier();
  }
#undef STAGE

  // epilogue: output rows = proj cols (n), output cols = x rows (m).
  // Per thread per (a,b): 4 consecutive proj-cols (d-quad) at fixed row m
  // -> RoPE pairs in-register, 8B bf16x4 stores.
#pragma unroll
  for (int a = 0; a < 3; ++a) {
    const int nq = n0 + wn * 48 + a * 16 + (lane >> 4) * 4;  // 4-aligned proj col
    const float4 bv = *(const float4*)(bias + nq);
    const int d = nq & 63;
    const int h = nq >> 7;
    unsigned short* base = ((nq >> 6) & 1) ? ko : qo;
    const float4 t01 = *(const float4*)(tab + 0);  // placeholder reload below per b (s-dep)
#pragma unroll
    for (int b = 0; b < 4; ++b) {
      const int mrow = m0 + wm * 64 + b * 16 + (lane & 15);
      const int s = mrow & (SS - 1);
      const int bidx = mrow >> 9;
      const float2* tp = tab + s * 32 + (d & 31);
      const float4 ta = *(const float4*)(tp);      // sin0,cos0,sin1,cos1
      const float4 tb = *(const float4*)(tp + 2);  // sin2,cos2,sin3,cos3
      float v0 = acc[a][b][0] + bv.x;
      float v1 = acc[a][b][1] + bv.y;
      float v2 = acc[a][b][2] + bv.z;
      float v3 = acc[a][b][3] + bv.w;
      float o0 = v0 * ta.y - v1 * ta.x;
      float o1 = v1 * ta.w + v0 * ta.z;
      float o2 = v2 * tb.y - v3 * tb.x;
      float o3 = v3 * tb.w + v2 * tb.z;
      us4 pk;
      pk[0] = f2bf(o0); pk[1] = f2bf(o1); pk[2] = f2bf(o2); pk[3] = f2bf(o3);
      *(us4*)(base + ((size_t)(bidx * NHEADS + h) * SS + s) * HSZ + d) = pk;
    }
    (void)t01;
  }
}

// ---- GEMM2: LDS-free. A-operand = K rows (n), B-operand = Q rows (m).
// Per thread per (ni,mi): 4 consecutive n at fixed m -> f32x4 nt stores.
__global__ __launch_bounds__(256) void k_logits(
    const unsigned short* __restrict__ q, const unsigned short* __restrict__ kk,
    const float* __restrict__ mask, float* __restrict__ out) {
  const int tid = threadIdx.x;
  const int lane = tid & 63, w = tid >> 6;
  const int bh = blockIdx.y;
  const int b = bh / NHEADS;
  const int m0 = (blockIdx.x >> 2) * 128, n0 = (blockIdx.x & 3) * 128;
  const char* qbase = (const char*)(q + (size_t)bh * SS * HSZ);
  const char* kbase = (const char*)(kk + (size_t)bh * SS * HSZ);

  int mrow[4], nrow[4];
#pragma unroll
  for (int i = 0; i < 4; ++i) {
    mrow[i] = m0 + (w >> 1) * 64 + i * 16 + (lane & 15);
    nrow[i] = n0 + (w & 1) * 64 + i * 16 + (lane & 15);
  }

  f32x4 acc[4][4];  // [ni][mi]
#pragma unroll
  for (int a = 0; a < 4; ++a)
#pragma unroll
    for (int bb = 0; bb < 4; ++bb)
      acc[a][bb] = (f32x4)(0.0f);

#pragma unroll
  for (int ks = 0; ks < 2; ++ks) {
    const int kboff = ks * 64 + (lane >> 4) * 16;
    bf16x8 kf[4], qf[4];
#pragma unroll
    for (int i = 0; i < 4; ++i)
      kf[i] = *(const bf16x8*)(kbase + (size_t)nrow[i] * 128 + kboff);
#pragma unroll
    for (int i = 0; i < 4; ++i)
      qf[i] = *(const bf16x8*)(qbase + (size_t)mrow[i] * 128 + kboff);
#pragma unroll
    for (int ni = 0; ni < 4; ++ni)
#pragma unroll
      for (int mi = 0; mi < 4; ++mi)
        acc[ni][mi] = __builtin_amdgcn_mfma_f32_16x16x32_bf16(kf[ni], qf[mi], acc[ni][mi], 0, 0, 0);
  }

#pragma unroll
  for (int mi = 0; mi < 4; ++mi) {
    const int m = mrow[mi];
    const float mr = mask[b * SS + m];
    float* orow = out + ((size_t)bh * SS + m) * SS;
#pragma unroll
    for (int ni = 0; ni < 4; ++ni) {
      const int nb = n0 + (w & 1) * 64 + ni * 16 + (lane >> 4) * 4;
      const float4 mc = *(const float4*)(mask + b * SS + nb);
      f32x4 res;
#pragma unroll
      for (int r = 0; r < 4; ++r) {
        float v = acc[ni][mi][r];
        const float mcv = (r == 0) ? mc.x : (r == 1) ? mc.y : (r == 2) ? mc.z : mc.w;
        v = v * mr - NEG_INF * (1.0f - mr);
        v = v * mcv - NEG_INF * (1.0f - mcv);
        if (m > nb + r) v -= NEG_INF;
        res[r] = v * 0.125f;
      }
      __builtin_nontemporal_store(res, (f32x4*)(orow + nb));
    }
  }
}

extern "C" void kernel_launch(void* const* d_in, const int* in_sizes, int n_in,
                              void* d_out, int out_size, void* d_ws, size_t ws_size,
                              hipStream_t stream) {
  const float* x = (const float*)d_in[0];
  const float* mask = (const float*)d_in[1];
  const float* W = (const float*)d_in[2];
  const float* bias = (const float*)d_in[3];
  float* out = (float*)d_out;

  char* ws = (char*)d_ws;
  float2* tab = (float2*)ws;                                               // 128 KB
  unsigned short* xb = (unsigned short*)(ws + 131072);                     // 8 MB
  unsigned short* wbt = (unsigned short*)(ws + 131072 + 8388608);          // 3 MB
  unsigned short* qo = (unsigned short*)(ws + 131072 + 8388608 + 3145728); // 6.29 MB
  unsigned short* ko = (unsigned short*)(ws + 131072 + 8388608 + 3145728 + 6291456);

  k_prep<<<dim3(64 + 4096 + 1536), dim3(256), 0, stream>>>(
      (const float4*)x, W, tab, (us4*)xb, wbt);
  k_proj<<<dim3(32, 16), dim3(256), 0, stream>>>(xb, wbt, bias, tab, qo, ko);
  k_logits<<<dim3(16, 96), dim3(256), 0, stream>>>(qo, ko, mask, out);
}

// Round 4
// 59.436 us; speedup vs baseline: 1.1920x; 1.1112x over previous
//
#include <hip/hip_runtime.h>
#include <stdint.h>
#include <stddef.h>

#define SS 512
#define HID 1024
#define NHEADS 12
#define HSZ 64
#define NPROJ 1536
#define NEG_INF 1000000000000.0f

typedef __attribute__((ext_vector_type(4))) float f32x4;
typedef __attribute__((ext_vector_type(8))) __bf16 bf16x8;
typedef __attribute__((ext_vector_type(4))) unsigned short us4;

typedef __attribute__((address_space(1))) unsigned char gu8;
typedef __attribute__((address_space(3))) unsigned char lu8;

static __device__ __forceinline__ void gld16(const void* g, void* l) {
  __builtin_amdgcn_global_load_lds((gu8*)(g), (lu8*)(l), 16, 0, 0);
}

static __device__ __forceinline__ unsigned short f2bf(float f) {
  union { float f; unsigned u; } x; x.f = f;
  unsigned r = x.u + 0x7fffu + ((x.u >> 16) & 1u);
  return (unsigned short)(r >> 16);
}

// ---- merged prep: [0,64) sincos table | [64,4160) x->bf16 | [4160,5696) W^T->bf16
__global__ __launch_bounds__(256) void k_prep(
    const float4* __restrict__ x, const float* __restrict__ W,
    float2* __restrict__ tab, us4* __restrict__ xb, unsigned short* __restrict__ wbt) {
  __shared__ float t[32][33];
  const int bid = blockIdx.x;
  const int tid = threadIdx.x;
  if (bid < 64) {
    int tt = bid * 256 + tid;
    int s = tt >> 5, i = tt & 31;
    float rate = powf(10000.0f, -(float)i / 32.0f);
    float sv, cv;
    sincosf((float)s * rate, &sv, &cv);
    tab[tt] = make_float2(sv, cv);
  } else if (bid < 64 + 4096) {
    int i = (bid - 64) * 256 + tid;
    float4 v = x[i];
    us4 o;
    o[0] = f2bf(v.x); o[1] = f2bf(v.y); o[2] = f2bf(v.z); o[3] = f2bf(v.w);
    xb[i] = o;
  } else {
    int flat = bid - (64 + 4096);
    int n0 = (flat % 48) * 32, k0 = (flat / 48) * 32;
    int tx = tid & 31, ty = tid >> 5;
#pragma unroll
    for (int i = 0; i < 4; ++i)
      t[ty + i * 8][tx] = W[(k0 + ty + i * 8) * NPROJ + n0 + tx];
    __syncthreads();
#pragma unroll
    for (int i = 0; i < 4; ++i)
      wbt[(n0 + ty + i * 8) * HID + (k0 + tx)] = f2bf(t[tx][ty + i * 8]);
  }
}

// ---- GEMM1: proj^T tiles. A-operand = W rows (n), B-operand = x rows (m).
// Tile: M=128 x-rows, N=96 proj-cols, BK=64. grid (32,16) = 512 blocks = 2/CU.
// Note: bi%8 = mt%8 -> each XCD sees 4 x-tiles (1MB) + W (3MB) ~= its L2. Already local.
// 2-phase double-buffered pipeline; XOR-swizzled LDS (linear dest + preswizzled src).
__global__ __launch_bounds__(256) void k_proj(
    const unsigned short* __restrict__ xb, const unsigned short* __restrict__ wbt,
    const float* __restrict__ bias, const float2* __restrict__ tab,
    unsigned short* __restrict__ qo, unsigned short* __restrict__ ko) {
  __shared__ __align__(16) unsigned short lA[2][128 * 64];  // x tile
  __shared__ __align__(16) unsigned short lB[2][96 * 64];   // W tile
  const int tid = threadIdx.x;
  const int lane = tid & 63, w = tid >> 6;
  const int wm = w >> 1, wn = w & 1;   // wm: m-half (64), wn: n-half (48)
  const int m0 = blockIdx.x * 128, n0 = blockIdx.y * 96;

  const char* aptr[4]; const char* bptr[3];
  int adst[4], bdst[3];
#pragma unroll
  for (int c = 0; c < 4; ++c) {
    int lin = (w * 4 + c) * 1024 + lane * 16;
    int row = lin >> 7, cb = lin & 127;
    aptr[c] = (const char*)(xb + (size_t)(m0 + row) * HID) + (cb ^ ((row & 7) << 4));
    adst[c] = (w * 4 + c) * 1024;
  }
#pragma unroll
  for (int c = 0; c < 3; ++c) {
    int lin = (w * 3 + c) * 1024 + lane * 16;
    int row = lin >> 7, cb = lin & 127;
    bptr[c] = (const char*)(wbt + (size_t)(n0 + row) * HID) + (cb ^ ((row & 7) << 4));
    bdst[c] = (w * 3 + c) * 1024;
  }

  f32x4 acc[3][4];
#pragma unroll
  for (int a = 0; a < 3; ++a)
#pragma unroll
    for (int b = 0; b < 4; ++b)
      acc[a][b] = (f32x4)(0.0f);

#define STAGE(buf, kt)                                                      \
  do {                                                                      \
    _Pragma("unroll") for (int c = 0; c < 4; ++c)                           \
        gld16(aptr[c] + (kt) * 128, (char*)(&lA[(buf)][0]) + adst[c]);      \
    _Pragma("unroll") for (int c = 0; c < 3; ++c)                           \
        gld16(bptr[c] + (kt) * 128, (char*)(&lB[(buf)][0]) + bdst[c]);      \
  } while (0)

  STAGE(0, 0);
  asm volatile("s_waitcnt vmcnt(0)" ::: "memory");
  __builtin_amdgcn_s_barrier();

  for (int kt = 0; kt < 16; ++kt) {
    const int cur = kt & 1;
    if (kt < 15) STAGE(cur ^ 1, kt + 1);
#pragma unroll
    for (int ks = 0; ks < 2; ++ks) {
      bf16x8 af[3], bf[4];
      const int kb = ks * 64 + (lane >> 4) * 16;
#pragma unroll
      for (int a = 0; a < 3; ++a) {
        int row = wn * 48 + a * 16 + (lane & 15);
        af[a] = *(const bf16x8*)((const char*)(&lB[cur][0]) + row * 128 + (kb ^ ((row & 7) << 4)));
      }
#pragma unroll
      for (int b = 0; b < 4; ++b) {
        int row = wm * 64 + b * 16 + (lane & 15);
        bf[b] = *(const bf16x8*)((const char*)(&lA[cur][0]) + row * 128 + (kb ^ ((row & 7) << 4)));
      }
#pragma unroll
      for (int a = 0; a < 3; ++a)
#pragma unroll
        for (int b = 0; b < 4; ++b)
          acc[a][b] = __builtin_amdgcn_mfma_f32_16x16x32_bf16(af[a], bf[b], acc[a][b], 0, 0, 0);
    }
    asm volatile("s_waitcnt vmcnt(0)" ::: "memory");
    __builtin_amdgcn_s_barrier();
  }
#undef STAGE

  // epilogue: per thread per (a,b): 4 consecutive proj-cols (d-quad) at fixed row m
  // -> RoPE pairs in-register, 8B bf16x4 stores.
#pragma unroll
  for (int a = 0; a < 3; ++a) {
    const int nq = n0 + wn * 48 + a * 16 + (lane >> 4) * 4;  // 4-aligned proj col
    const float4 bv = *(const float4*)(bias + nq);
    const int d = nq & 63;
    const int h = nq >> 7;
    unsigned short* base = ((nq >> 6) & 1) ? ko : qo;
#pragma unroll
    for (int b = 0; b < 4; ++b) {
      const int mrow = m0 + wm * 64 + b * 16 + (lane & 15);
      const int s = mrow & (SS - 1);
      const int bidx = mrow >> 9;
      const float2* tp = tab + s * 32 + (d & 31);
      const float4 ta = *(const float4*)(tp);      // sin0,cos0,sin1,cos1
      const float4 tb = *(const float4*)(tp + 2);  // sin2,cos2,sin3,cos3
      float v0 = acc[a][b][0] + bv.x;
      float v1 = acc[a][b][1] + bv.y;
      float v2 = acc[a][b][2] + bv.z;
      float v3 = acc[a][b][3] + bv.w;
      float o0 = v0 * ta.y - v1 * ta.x;
      float o1 = v1 * ta.w + v0 * ta.z;
      float o2 = v2 * tb.y - v3 * tb.x;
      float o3 = v3 * tb.w + v2 * tb.z;
      us4 pk;
      pk[0] = f2bf(o0); pk[1] = f2bf(o1); pk[2] = f2bf(o2); pk[3] = f2bf(o3);
      *(us4*)(base + ((size_t)(bidx * NHEADS + h) * SS + s) * HSZ + d) = pk;
    }
  }
}

// ---- GEMM2: LDS-free. A-operand = K rows (n), B-operand = Q rows (m).
// NORMAL stores (L2 merges the stride-2KB 16B pieces into full lines; nt bypassed
// L2 and caused ~4x HBM write amplification).
__global__ __launch_bounds__(256) void k_logits(
    const unsigned short* __restrict__ q, const unsigned short* __restrict__ kk,
    const float* __restrict__ mask, float* __restrict__ out) {
  const int tid = threadIdx.x;
  const int lane = tid & 63, w = tid >> 6;
  const int bh = blockIdx.y;
  const int b = bh / NHEADS;
  const int m0 = (blockIdx.x >> 2) * 128, n0 = (blockIdx.x & 3) * 128;
  const char* qbase = (const char*)(q + (size_t)bh * SS * HSZ);
  const char* kbase = (const char*)(kk + (size_t)bh * SS * HSZ);

  int mrow[4], nrow[4];
#pragma unroll
  for (int i = 0; i < 4; ++i) {
    mrow[i] = m0 + (w >> 1) * 64 + i * 16 + (lane & 15);
    nrow[i] = n0 + (w & 1) * 64 + i * 16 + (lane & 15);
  }

  f32x4 acc[4][4];  // [ni][mi]
#pragma unroll
  for (int a = 0; a < 4; ++a)
#pragma unroll
    for (int bb = 0; bb < 4; ++bb)
      acc[a][bb] = (f32x4)(0.0f);

#pragma unroll
  for (int ks = 0; ks < 2; ++ks) {
    const int kboff = ks * 64 + (lane >> 4) * 16;
    bf16x8 kf[4], qf[4];
#pragma unroll
    for (int i = 0; i < 4; ++i)
      kf[i] = *(const bf16x8*)(kbase + (size_t)nrow[i] * 128 + kboff);
#pragma unroll
    for (int i = 0; i < 4; ++i)
      qf[i] = *(const bf16x8*)(qbase + (size_t)mrow[i] * 128 + kboff);
#pragma unroll
    for (int ni = 0; ni < 4; ++ni)
#pragma unroll
      for (int mi = 0; mi < 4; ++mi)
        acc[ni][mi] = __builtin_amdgcn_mfma_f32_16x16x32_bf16(kf[ni], qf[mi], acc[ni][mi], 0, 0, 0);
  }

#pragma unroll
  for (int mi = 0; mi < 4; ++mi) {
    const int m = mrow[mi];
    const float mr = mask[b * SS + m];
    float* orow = out + ((size_t)bh * SS + m) * SS;
#pragma unroll
    for (int ni = 0; ni < 4; ++ni) {
      const int nb = n0 + (w & 1) * 64 + ni * 16 + (lane >> 4) * 4;
      const float4 mc = *(const float4*)(mask + b * SS + nb);
      f32x4 res;
#pragma unroll
      for (int r = 0; r < 4; ++r) {
        float v = acc[ni][mi][r];
        const float mcv = (r == 0) ? mc.x : (r == 1) ? mc.y : (r == 2) ? mc.z : mc.w;
        v = v * mr - NEG_INF * (1.0f - mr);
        v = v * mcv - NEG_INF * (1.0f - mcv);
        if (m > nb + r) v -= NEG_INF;
        res[r] = v * 0.125f;
      }
      *(f32x4*)(orow + nb) = res;
    }
  }
}

extern "C" void kernel_launch(void* const* d_in, const int* in_sizes, int n_in,
                              void* d_out, int out_size, void* d_ws, size_t ws_size,
                              hipStream_t stream) {
  const float* x = (const float*)d_in[0];
  const float* mask = (const float*)d_in[1];
  const float* W = (const float*)d_in[2];
  const float* bias = (const float*)d_in[3];
  float* out = (float*)d_out;

  char* ws = (char*)d_ws;
  float2* tab = (float2*)ws;                                               // 128 KB
  unsigned short* xb = (unsigned short*)(ws + 131072);                     // 8 MB
  unsigned short* wbt = (unsigned short*)(ws + 131072 + 8388608);          // 3 MB
  unsigned short* qo = (unsigned short*)(ws + 131072 + 8388608 + 3145728); // 6.29 MB
  unsigned short* ko = (unsigned short*)(ws + 131072 + 8388608 + 3145728 + 6291456);

  k_prep<<<dim3(64 + 4096 + 1536), dim3(256), 0, stream>>>(
      (const float4*)x, W, tab, (us4*)xb, wbt);
  k_proj<<<dim3(32, 16), dim3(256), 0, stream>>>(xb, wbt, bias, tab, qo, ko);
  k_logits<<<dim3(16, 96), dim3(256), 0, stream>>>(qo, ko, mask, out);
}

// Round 5
// 59.264 us; speedup vs baseline: 1.1955x; 1.0029x over previous
//
#include <hip/hip_runtime.h>
#include <stdint.h>
#include <stddef.h>

#define SS 512
#define HID 1024
#define NHEADS 12
#define HSZ 64
#define NPROJ 1536
#define NEG_INF 1000000000000.0f

typedef __attribute__((ext_vector_type(4))) float f32x4;
typedef __attribute__((ext_vector_type(8))) __bf16 bf16x8;
typedef __attribute__((ext_vector_type(4))) unsigned short us4;

typedef __attribute__((address_space(1))) unsigned char gu8;
typedef __attribute__((address_space(3))) unsigned char lu8;

static __device__ __forceinline__ void gld16(const void* g, void* l) {
  __builtin_amdgcn_global_load_lds((gu8*)(g), (lu8*)(l), 16, 0, 0);
}

static __device__ __forceinline__ unsigned short f2bf(float f) {
  union { float f; unsigned u; } x; x.f = f;
  unsigned r = x.u + 0x7fffu + ((x.u >> 16) & 1u);
  return (unsigned short)(r >> 16);
}

// ---- merged prep: [0,64) sincos table | [64,4160) x->bf16 | [4160,5696) W^T->bf16
__global__ __launch_bounds__(256) void k_prep(
    const float4* __restrict__ x, const float* __restrict__ W,
    float2* __restrict__ tab, us4* __restrict__ xb, unsigned short* __restrict__ wbt) {
  __shared__ float t[32][33];
  const int bid = blockIdx.x;
  const int tid = threadIdx.x;
  if (bid < 64) {
    int tt = bid * 256 + tid;
    int s = tt >> 5, i = tt & 31;
    float rate = powf(10000.0f, -(float)i / 32.0f);
    float sv, cv;
    sincosf((float)s * rate, &sv, &cv);
    tab[tt] = make_float2(sv, cv);
  } else if (bid < 64 + 4096) {
    int i = (bid - 64) * 256 + tid;
    float4 v = x[i];
    us4 o;
    o[0] = f2bf(v.x); o[1] = f2bf(v.y); o[2] = f2bf(v.z); o[3] = f2bf(v.w);
    xb[i] = o;
  } else {
    int flat = bid - (64 + 4096);
    int n0 = (flat % 48) * 32, k0 = (flat / 48) * 32;
    int tx = tid & 31, ty = tid >> 5;
#pragma unroll
    for (int i = 0; i < 4; ++i)
      t[ty + i * 8][tx] = W[(k0 + ty + i * 8) * NPROJ + n0 + tx];
    __syncthreads();
#pragma unroll
    for (int i = 0; i < 4; ++i)
      wbt[(n0 + ty + i * 8) * HID + (k0 + tx)] = f2bf(t[tx][ty + i * 8]);
  }
}

// ---- GEMM1: proj^T tiles. A-operand = W rows (n), B-operand = x rows (m).
// Tile: M=128, N=96, BK=64. grid (32,16) = 512 blocks = 2/CU.
// T4 counted-vmcnt pipeline: next-tile global_load_lds stays in flight across
// the barrier (wait vmcnt(7) = older stage only; never drain to 0 mid-loop).
__global__ __launch_bounds__(256) void k_proj(
    const unsigned short* __restrict__ xb, const unsigned short* __restrict__ wbt,
    const float* __restrict__ bias, const float2* __restrict__ tab,
    unsigned short* __restrict__ qo, unsigned short* __restrict__ ko) {
  __shared__ __align__(16) unsigned short lA[2][128 * 64];  // x tile
  __shared__ __align__(16) unsigned short lB[2][96 * 64];   // W tile
  const int tid = threadIdx.x;
  const int lane = tid & 63, w = tid >> 6;
  const int wm = w >> 1, wn = w & 1;
  const int m0 = blockIdx.x * 128, n0 = blockIdx.y * 96;

  const char* aptr[4]; const char* bptr[3];
  int adst[4], bdst[3];
#pragma unroll
  for (int c = 0; c < 4; ++c) {
    int lin = (w * 4 + c) * 1024 + lane * 16;
    int row = lin >> 7, cb = lin & 127;
    aptr[c] = (const char*)(xb + (size_t)(m0 + row) * HID) + (cb ^ ((row & 7) << 4));
    adst[c] = (w * 4 + c) * 1024;
  }
#pragma unroll
  for (int c = 0; c < 3; ++c) {
    int lin = (w * 3 + c) * 1024 + lane * 16;
    int row = lin >> 7, cb = lin & 127;
    bptr[c] = (const char*)(wbt + (size_t)(n0 + row) * HID) + (cb ^ ((row & 7) << 4));
    bdst[c] = (w * 3 + c) * 1024;
  }

  f32x4 acc[3][4];
#pragma unroll
  for (int a = 0; a < 3; ++a)
#pragma unroll
    for (int b = 0; b < 4; ++b)
      acc[a][b] = (f32x4)(0.0f);

#define STAGE(buf, kt)                                                      \
  do {                                                                      \
    _Pragma("unroll") for (int c = 0; c < 4; ++c)                           \
        gld16(aptr[c] + (kt) * 128, (char*)(&lA[(buf)][0]) + adst[c]);      \
    _Pragma("unroll") for (int c = 0; c < 3; ++c)                           \
        gld16(bptr[c] + (kt) * 128, (char*)(&lB[(buf)][0]) + bdst[c]);      \
  } while (0)

  __builtin_amdgcn_sched_barrier(0);
  STAGE(0, 0);

  for (int kt = 0; kt < 16; ++kt) {
    const int cur = kt & 1;
    if (kt < 15) {
      STAGE(cur ^ 1, kt + 1);
      asm volatile("s_waitcnt vmcnt(7)" ::: "memory");  // older stage (cur) done; new 7 in flight
    } else {
      asm volatile("s_waitcnt vmcnt(0)" ::: "memory");
    }
    __builtin_amdgcn_s_barrier();
#pragma unroll
    for (int ks = 0; ks < 2; ++ks) {
      bf16x8 af[3], bf[4];
      const int kb = ks * 64 + (lane >> 4) * 16;
#pragma unroll
      for (int a = 0; a < 3; ++a) {
        int row = wn * 48 + a * 16 + (lane & 15);
        af[a] = *(const bf16x8*)((const char*)(&lB[cur][0]) + row * 128 + (kb ^ ((row & 7) << 4)));
      }
#pragma unroll
      for (int b = 0; b < 4; ++b) {
        int row = wm * 64 + b * 16 + (lane & 15);
        bf[b] = *(const bf16x8*)((const char*)(&lA[cur][0]) + row * 128 + (kb ^ ((row & 7) << 4)));
      }
#pragma unroll
      for (int a = 0; a < 3; ++a)
#pragma unroll
        for (int b = 0; b < 4; ++b)
          acc[a][b] = __builtin_amdgcn_mfma_f32_16x16x32_bf16(af[a], bf[b], acc[a][b], 0, 0, 0);
    }
    asm volatile("s_waitcnt lgkmcnt(0)" ::: "memory");  // my ds_reads of cur complete
    __builtin_amdgcn_s_barrier();                        // safe to overwrite cur next iter
  }
#undef STAGE
  __builtin_amdgcn_sched_barrier(0);  // keep epilogue VMEM out of the counted loop

  // epilogue: per thread per (a,b): 4 consecutive proj-cols (d-quad) at fixed row m
#pragma unroll
  for (int a = 0; a < 3; ++a) {
    const int nq = n0 + wn * 48 + a * 16 + (lane >> 4) * 4;
    const float4 bv = *(const float4*)(bias + nq);
    const int d = nq & 63;
    const int h = nq >> 7;
    unsigned short* base = ((nq >> 6) & 1) ? ko : qo;
#pragma unroll
    for (int b = 0; b < 4; ++b) {
      const int mrow = m0 + wm * 64 + b * 16 + (lane & 15);
      const int s = mrow & (SS - 1);
      const int bidx = mrow >> 9;
      const float2* tp = tab + s * 32 + (d & 31);
      const float4 ta = *(const float4*)(tp);
      const float4 tb = *(const float4*)(tp + 2);
      float v0 = acc[a][b][0] + bv.x;
      float v1 = acc[a][b][1] + bv.y;
      float v2 = acc[a][b][2] + bv.z;
      float v3 = acc[a][b][3] + bv.w;
      float o0 = v0 * ta.y - v1 * ta.x;
      float o1 = v1 * ta.w + v0 * ta.z;
      float o2 = v2 * tb.y - v3 * tb.x;
      float o3 = v3 * tb.w + v2 * tb.z;
      us4 pk;
      pk[0] = f2bf(o0); pk[1] = f2bf(o1); pk[2] = f2bf(o2); pk[3] = f2bf(o3);
      *(us4*)(base + ((size_t)(bidx * NHEADS + h) * SS + s) * HSZ + d) = pk;
    }
  }
}

// ---- GEMM2: LDS-free. A-operand = K rows (n), B-operand = Q rows (m).
__global__ __launch_bounds__(256) void k_logits(
    const unsigned short* __restrict__ q, const unsigned short* __restrict__ kk,
    const float* __restrict__ mask, float* __restrict__ out) {
  const int tid = threadIdx.x;
  const int lane = tid & 63, w = tid >> 6;
  const int bh = blockIdx.y;
  const int b = bh / NHEADS;
  const int m0 = (blockIdx.x >> 2) * 128, n0 = (blockIdx.x & 3) * 128;
  const char* qbase = (const char*)(q + (size_t)bh * SS * HSZ);
  const char* kbase = (const char*)(kk + (size_t)bh * SS * HSZ);

  int mrow[4], nrow[4];
#pragma unroll
  for (int i = 0; i < 4; ++i) {
    mrow[i] = m0 + (w >> 1) * 64 + i * 16 + (lane & 15);
    nrow[i] = n0 + (w & 1) * 64 + i * 16 + (lane & 15);
  }

  f32x4 acc[4][4];  // [ni][mi]
#pragma unroll
  for (int a = 0; a < 4; ++a)
#pragma unroll
    for (int bb = 0; bb < 4; ++bb)
      acc[a][bb] = (f32x4)(0.0f);

#pragma unroll
  for (int ks = 0; ks < 2; ++ks) {
    const int kboff = ks * 64 + (lane >> 4) * 16;
    bf16x8 kf[4], qf[4];
#pragma unroll
    for (int i = 0; i < 4; ++i)
      kf[i] = *(const bf16x8*)(kbase + (size_t)nrow[i] * 128 + kboff);
#pragma unroll
    for (int i = 0; i < 4; ++i)
      qf[i] = *(const bf16x8*)(qbase + (size_t)mrow[i] * 128 + kboff);
#pragma unroll
    for (int ni = 0; ni < 4; ++ni)
#pragma unroll
      for (int mi = 0; mi < 4; ++mi)
        acc[ni][mi] = __builtin_amdgcn_mfma_f32_16x16x32_bf16(kf[ni], qf[mi], acc[ni][mi], 0, 0, 0);
  }

#pragma unroll
  for (int mi = 0; mi < 4; ++mi) {
    const int m = mrow[mi];
    const float mr = mask[b * SS + m];
    float* orow = out + ((size_t)bh * SS + m) * SS;
#pragma unroll
    for (int ni = 0; ni < 4; ++ni) {
      const int nb = n0 + (w & 1) * 64 + ni * 16 + (lane >> 4) * 4;
      const float4 mc = *(const float4*)(mask + b * SS + nb);
      f32x4 res;
#pragma unroll
      for (int r = 0; r < 4; ++r) {
        float v = acc[ni][mi][r];
        const float mcv = (r == 0) ? mc.x : (r == 1) ? mc.y : (r == 2) ? mc.z : mc.w;
        v = v * mr - NEG_INF * (1.0f - mr);
        v = v * mcv - NEG_INF * (1.0f - mcv);
        if (m > nb + r) v -= NEG_INF;
        res[r] = v * 0.125f;
      }
      *(f32x4*)(orow + nb) = res;
    }
  }
}

extern "C" void kernel_launch(void* const* d_in, const int* in_sizes, int n_in,
                              void* d_out, int out_size, void* d_ws, size_t ws_size,
                              hipStream_t stream) {
  const float* x = (const float*)d_in[0];
  const float* mask = (const float*)d_in[1];
  const float* W = (const float*)d_in[2];
  const float* bias = (const float*)d_in[3];
  float* out = (float*)d_out;

  char* ws = (char*)d_ws;
  float2* tab = (float2*)ws;                                               // 128 KB
  unsigned short* xb = (unsigned short*)(ws + 131072);                     // 8 MB
  unsigned short* wbt = (unsigned short*)(ws + 131072 + 8388608);          // 3 MB
  unsigned short* qo = (unsigned short*)(ws + 131072 + 8388608 + 3145728); // 6.29 MB
  unsigned short* ko = (unsigned short*)(ws + 131072 + 8388608 + 3145728 + 6291456);

  k_prep<<<dim3(64 + 4096 + 1536), dim3(256), 0, stream>>>(
      (const float4*)x, W, tab, (us4*)xb, wbt);
  k_proj<<<dim3(32, 16), dim3(256), 0, stream>>>(xb, wbt, bias, tab, qo, ko);
  k_logits<<<dim3(16, 96), dim3(256), 0, stream>>>(qo, ko, mask, out);
}